// Round 5
// baseline (239.651 us; speedup 1.0000x reference)
//
#include <hip/hip_runtime.h>
#include <math.h>

#define N_NODES 50000
#define N_EDGES 800000
#define N_GRAPHS 64
#define DIM 128
#define OUTD 16

// bucketed CSR build: 256 nodes per bucket, STATIC bucket regions
#define BSHIFT 8
#define BNODES 256
#define NBUCK ((N_NODES + BNODES - 1) / BNODES)   // 196
#define TILE 2048                                  // edges per binning block
#define RCAP 8192                                  // LDS stage capacity (entries)
#define BSLOT 4864                                 // static region (mean 4096 + 12 sigma)
#define GEMMB 256                                  // persistent gemm blocks
#define BIN_GRID ((N_EDGES + TILE - 1) / TILE)     // 391

typedef __attribute__((ext_vector_type(8))) short short8;
typedef __attribute__((ext_vector_type(4))) float f32x4;

// ---- bf16 helpers (round-to-nearest-even; values are finite) ----
static __device__ __forceinline__ unsigned short f2bf(float f) {
    unsigned u = __float_as_uint(f);
    u += 0x7fffu + ((u >> 16) & 1u);
    return (unsigned short)(u >> 16);
}
static __device__ __forceinline__ float bfl(unsigned u) {
    return __uint_as_float(u << 16);
}
static __device__ __forceinline__ float bfh(unsigned u) {
    return __uint_as_float(u & 0xffff0000u);
}

// ---------------- init: zero bucket counts + pool; preconvert W2 ----------
// W2f layout = gemm fragment order: uint[((kstep*8+ct)*64 + quad*16+(n&15))*4 + jw]
// holding bf16(W2[k][n]) | bf16(W2[k+1][n])<<16 for k=2*kp.
__global__ __launch_bounds__(256) void k_init(int* __restrict__ bcnt,
                                              float* __restrict__ pool,
                                              const float* __restrict__ W2,
                                              unsigned* __restrict__ W2f) {
    int tid = threadIdx.x;
    if (tid < NBUCK) bcnt[tid] = 0;
    for (int i = tid; i < N_GRAPHS * DIM; i += 256) pool[i] = 0.f;
    for (int idx = tid; idx < (DIM / 2) * DIM; idx += 256) {
        int kp = idx >> 7;          // 0..63
        int n  = idx & 127;
        int k  = kp * 2;
        int kstep = kp >> 4;
        int quad  = (kp >> 2) & 3;
        int jw    = kp & 3;
        int ct    = n >> 4;
        unsigned vlo = f2bf(W2[(size_t)k * DIM + n]);
        unsigned vhi = f2bf(W2[(size_t)(k + 1) * DIM + n]);
        W2f[(((kstep * 8 + ct) * 64) + quad * 16 + (n & 15)) * 4 + jw] = vlo | (vhi << 16);
    }
}

// ---------------- shared GEMM body (W in LDS, MFMA, LDS C-stage) ----------
template <int BF16IN>
static __device__ __forceinline__ void gemm_body(const void* __restrict__ Av,
                                                 const float* __restrict__ Wg,
                                                 unsigned short* __restrict__ C,
                                                 int nrows,
                                                 unsigned* smemW, unsigned* smemC,
                                                 int tile0, int tstride) {
    unsigned* Wl = smemW;
    {
        int t = threadIdx.x;
        int p = t & 63;
        int kp = p * 2;
        int n0 = (t >> 6) * 32;
        int kstep = kp >> 5;
        int quad = (kp >> 3) & 3;
        int jw = (kp & 7) >> 1;
        const float* r0 = Wg + (size_t)kp * DIM;
        const float* r1 = r0 + DIM;
        int rot = (p >> 2) & 7;
#pragma unroll
        for (int i4 = 0; i4 < 8; ++i4) {
            int nb = ((i4 + rot) & 7) * 4;
            int n = n0 + nb;
            float4 lo = *(const float4*)(r0 + n);
            float4 hi = *(const float4*)(r1 + n);
            const float* lp = &lo.x;
            const float* hp = &hi.x;
#pragma unroll
            for (int ii = 0; ii < 4; ++ii) {
                int nn = n + ii;
                int ct = nn >> 4;
                int l  = quad * 16 + (nn & 15);
                unsigned vlo = f2bf(lp[ii]);
                unsigned vhi = f2bf(hp[ii]);
                Wl[(((kstep * 8 + ct) * 64) + l) * 4 + jw] = vlo | (vhi << 16);
            }
        }
    }
    __syncthreads();

    int wid  = threadIdx.x >> 6;
    int lane = threadIdx.x & 63;
    int m    = lane & 15;
    int quad = lane >> 4;
    const short8* Wf = (const short8*)Wl;
    unsigned short* cs = (unsigned short*)smemC + wid * 4352;  // 32 rows x 136 ushorts
    const unsigned char* cb = (const unsigned char*)smemC + wid * 8704;

    int ntiles = (nrows + 127) / 128;
    for (int tile = tile0; tile < ntiles; tile += tstride) {
        int row0 = tile * 128 + wid * 32;
        if (row0 >= nrows) continue;

        int rA = row0 + m;      if (rA >= nrows) rA = nrows - 1;
        int rB = row0 + 16 + m; if (rB >= nrows) rB = nrows - 1;

        short8 af0[4], af1[4];
        if (BF16IN) {
            const unsigned short* arowA = (const unsigned short*)Av + (size_t)rA * DIM + quad * 8;
            const unsigned short* arowB = (const unsigned short*)Av + (size_t)rB * DIM + quad * 8;
#pragma unroll
            for (int ks = 0; ks < 4; ++ks) {
                af0[ks] = *(const short8*)(arowA + ks * 32);
                af1[ks] = *(const short8*)(arowB + ks * 32);
            }
        } else {
            const float* arowA = (const float*)Av + (size_t)rA * DIM + quad * 8;
            const float* arowB = (const float*)Av + (size_t)rB * DIM + quad * 8;
#pragma unroll
            for (int ks = 0; ks < 4; ++ks) {
                float4 lo = *(const float4*)(arowA + ks * 32);
                float4 hi = *(const float4*)(arowA + ks * 32 + 4);
                short8 f;
                f[0] = (short)f2bf(lo.x); f[1] = (short)f2bf(lo.y);
                f[2] = (short)f2bf(lo.z); f[3] = (short)f2bf(lo.w);
                f[4] = (short)f2bf(hi.x); f[5] = (short)f2bf(hi.y);
                f[6] = (short)f2bf(hi.z); f[7] = (short)f2bf(hi.w);
                af0[ks] = f;
                lo = *(const float4*)(arowB + ks * 32);
                hi = *(const float4*)(arowB + ks * 32 + 4);
                f[0] = (short)f2bf(lo.x); f[1] = (short)f2bf(lo.y);
                f[2] = (short)f2bf(lo.z); f[3] = (short)f2bf(lo.w);
                f[4] = (short)f2bf(hi.x); f[5] = (short)f2bf(hi.y);
                f[6] = (short)f2bf(hi.z); f[7] = (short)f2bf(hi.w);
                af1[ks] = f;
            }
        }

        f32x4 acc0[8], acc1[8];
#pragma unroll
        for (int ct = 0; ct < 8; ++ct) {
            acc0[ct] = (f32x4){0.f, 0.f, 0.f, 0.f};
            acc1[ct] = (f32x4){0.f, 0.f, 0.f, 0.f};
        }

#pragma unroll
        for (int ks = 0; ks < 4; ++ks) {
#pragma unroll
            for (int ct = 0; ct < 8; ++ct) {
                short8 bfrag = Wf[(ks * 8 + ct) * 64 + lane];
                acc0[ct] = __builtin_amdgcn_mfma_f32_16x16x32_bf16(af0[ks], bfrag, acc0[ct], 0, 0, 0);
                acc1[ct] = __builtin_amdgcn_mfma_f32_16x16x32_bf16(af1[ks], bfrag, acc1[ct], 0, 0, 0);
            }
        }

#pragma unroll
        for (int ct = 0; ct < 8; ++ct) {
#pragma unroll
            for (int reg = 0; reg < 4; ++reg) {
                cs[(quad * 4 + reg) * 136 + ct * 16 + m]      = f2bf(acc0[ct][reg]);
                cs[(16 + quad * 4 + reg) * 136 + ct * 16 + m] = f2bf(acc1[ct][reg]);
            }
        }
#pragma unroll
        for (int i = 0; i < 8; ++i) {
            int rg = i * 4 + quad;
            int r = row0 + rg;
            if (r < nrows) {
                uint4 vv = *(const uint4*)(cb + rg * 272 + m * 16);
                *((uint4*)(C + (size_t)r * DIM) + m) = vv;
            }
        }
    }
}

// ---------------- fused layer-1 GEMM + binA (independent work) ------------
__global__ __launch_bounds__(256) void k_fused1(const float* __restrict__ A,
                                                const float* __restrict__ Wg,
                                                unsigned short* __restrict__ C,
                                                int nrows,
                                                const int* __restrict__ src,
                                                const int* __restrict__ dstp,
                                                int* __restrict__ bcnt,
                                                unsigned* __restrict__ bucket_arr) {
    __shared__ unsigned smemW[32768 / 4];
    __shared__ unsigned smemC[34816 / 4];
    if (blockIdx.x >= GEMMB) {
        int* cnt  = (int*)smemW;
        int* base = cnt + NBUCK;
        int tile0 = (blockIdx.x - GEMMB) * TILE;
        for (int i = threadIdx.x; i < NBUCK; i += 256) cnt[i] = 0;
        __syncthreads();
#pragma unroll
        for (int j = 0; j < TILE / 512; ++j) {
            int e = tile0 + j * 512 + threadIdx.x * 2;
            if (e < N_EDGES) {
                int2 d = *(const int2*)(dstp + e);
                atomicAdd(&cnt[d.x >> BSHIFT], 1);
                atomicAdd(&cnt[d.y >> BSHIFT], 1);
            }
        }
        __syncthreads();
        for (int i = threadIdx.x; i < NBUCK; i += 256) {
            int c = cnt[i];
            base[i] = i * BSLOT + (c ? atomicAdd(&bcnt[i], c) : 0);
            cnt[i] = 0;   // reuse as local cursor
        }
        __syncthreads();
#pragma unroll
        for (int j = 0; j < TILE / 512; ++j) {
            int e = tile0 + j * 512 + threadIdx.x * 2;
            if (e < N_EDGES) {
                int2 s = *(const int2*)(src + e);
                int2 d = *(const int2*)(dstp + e);
                int b0 = d.x >> BSHIFT, b1 = d.y >> BSHIFT;
                int p0 = base[b0] + atomicAdd(&cnt[b0], 1);
                bucket_arr[p0] = (unsigned)s.x | ((unsigned)(d.x & 255) << 16);
                int p1 = base[b1] + atomicAdd(&cnt[b1], 1);
                bucket_arr[p1] = (unsigned)s.y | ((unsigned)(d.y & 255) << 16);
            }
        }
        return;
    }
    gemm_body<0>(A, Wg, C, nrows, smemW, smemC, blockIdx.x, GEMMB);
}

// ---------------- Pass B: bases scan + fine scatter + degree/rowoff/dis ----
// NEW: per-node edge lists are SORTED BY SRC before write-out. All agg
// blocks then walk ascending src ids roughly in lockstep, so the chip-wide
// gather window concentrates in a sliding ~1-2MB range of H rows that fits
// the per-XCD L2 -> fewer L2 misses, lower average gather latency.
__global__ __launch_bounds__(256) void k_binB(const unsigned* __restrict__ barr,
                                              const int* __restrict__ bcnt,
                                              int* __restrict__ row_off,
                                              float* __restrict__ dis,
                                              unsigned short* __restrict__ csr) {
    __shared__ unsigned raw[RCAP];
    __shared__ unsigned short stage[RCAP];
    __shared__ int hist[BNODES];
    __shared__ int scn[BNODES];
    __shared__ int borig[256], bscan[256];
    int tid = threadIdx.x;
    int b = blockIdx.x;
    int n0 = b << BSHIFT;

    int cv = (tid < NBUCK) ? bcnt[tid] : 0;
    borig[tid] = cv;
    bscan[tid] = cv;
    __syncthreads();
    for (int off = 1; off < 256; off <<= 1) {
        int t = (tid >= off) ? bscan[tid - off] : 0;
        __syncthreads();
        bscan[tid] += t;
        __syncthreads();
    }
    int rbase = bscan[b] - borig[b];
    int len = borig[b];
    const unsigned* bin = barr + (size_t)b * BSLOT;

    hist[tid] = 0;
    __syncthreads();
    for (int i = tid; i < len; i += 256) {
        unsigned ed = bin[i];
        if (i < RCAP) raw[i] = ed;
        atomicAdd(&hist[ed >> 16], 1);
    }
    __syncthreads();
    int v = hist[tid];
    scn[tid] = v;
    __syncthreads();
    for (int off = 1; off < 256; off <<= 1) {
        int t = (tid >= off) ? scn[tid - off] : 0;
        __syncthreads();
        scn[tid] += t;
        __syncthreads();
    }
    int excl = scn[tid] - v;
    int n = n0 + tid;
    if (n < N_NODES) {
        row_off[n] = rbase + excl;
        dis[n] = rsqrtf((float)(v + 1));   // +1 = self-loop
    }
    if (b == NBUCK - 1 && tid == 0) row_off[N_NODES] = N_EDGES;
    hist[tid] = excl;   // reuse as cursor
    __syncthreads();
    // len <= BSLOT (4864) < RCAP (8192): everything passes through stage[]
    for (int i = tid; i < len; i += 256) {
        unsigned ed = (i < RCAP) ? raw[i] : bin[i];
        int p = atomicAdd(&hist[ed >> 16], 1);
        unsigned short sv = (unsigned short)(ed & 0xffffu);
        if (p < RCAP) stage[p] = sv;
        else csr[rbase + p] = sv;
    }
    __syncthreads();
    // per-node insertion sort by src id (thread tid owns segment [excl, excl+v))
    {
        int s0 = excl, s1 = excl + v;
        for (int i = s0 + 1; i < s1; ++i) {
            unsigned short key = stage[i];
            int j = i - 1;
            while (j >= s0 && stage[j] > key) { stage[j + 1] = stage[j]; --j; }
            stage[j + 1] = key;
        }
    }
    __syncthreads();
    int lim = min(len, RCAP);
    for (int i = tid; i < lim; i += 256)
        csr[rbase + i] = stage[i];
}

// ---------------- Aggregation (pull, bf16 gather) ----------------
// Proven R0 structure: 16 lanes/node, 16 nodes/block, static mapping,
// fat register accumulators (4 banks x 8) keep 4 gathers in flight.
// Edge lists are src-sorted (see k_binB) for L2 window locality.
// MODE==2 (layer 1): fuse layer-2 GEMM. MODE==1 (layer 2): fuse mean-pool.
template <int MODE>
__global__ __launch_bounds__(256) void k_agg(const uint4* __restrict__ Hb4,
                                             const int* __restrict__ row_off,
                                             const unsigned short* __restrict__ csr,
                                             const float* __restrict__ dis,
                                             const float* __restrict__ bias,
                                             uint4* __restrict__ out,
                                             const int* __restrict__ batch,
                                             float* __restrict__ pool,
                                             const short8* __restrict__ W2f) {
    __shared__ unsigned char smem[8768];
    int lane = threadIdx.x & 15;
    int nl   = threadIdx.x >> 4;      // node-local 0..15
    int node = blockIdx.x * 16 + nl;  // grid exact: 3125*16 = 50000

    float dn = dis[node];
    float wself = dn * dn;
    uint4 hp = Hb4[(size_t)node * 16 + lane];
    float a0[8], a1[8], a2[8], a3[8];
    a0[0] = wself * bfl(hp.x); a0[1] = wself * bfh(hp.x);
    a0[2] = wself * bfl(hp.y); a0[3] = wself * bfh(hp.y);
    a0[4] = wself * bfl(hp.z); a0[5] = wself * bfh(hp.z);
    a0[6] = wself * bfl(hp.w); a0[7] = wself * bfh(hp.w);
#pragma unroll
    for (int j = 0; j < 8; ++j) { a1[j] = 0.f; a2[j] = 0.f; a3[j] = 0.f; }

    int e = row_off[node], e1 = row_off[node + 1];
    for (; e + 4 <= e1; e += 4) {
        int s0 = csr[e];     int s1 = csr[e + 1];
        int s2 = csr[e + 2]; int s3 = csr[e + 3];
        uint4 g0 = Hb4[(size_t)s0 * 16 + lane];
        uint4 g1 = Hb4[(size_t)s1 * 16 + lane];
        uint4 g2 = Hb4[(size_t)s2 * 16 + lane];
        uint4 g3 = Hb4[(size_t)s3 * 16 + lane];
        float w0 = dn * dis[s0], w1 = dn * dis[s1];
        float w2 = dn * dis[s2], w3 = dn * dis[s3];
        a0[0] = fmaf(w0, bfl(g0.x), a0[0]); a0[1] = fmaf(w0, bfh(g0.x), a0[1]);
        a0[2] = fmaf(w0, bfl(g0.y), a0[2]); a0[3] = fmaf(w0, bfh(g0.y), a0[3]);
        a0[4] = fmaf(w0, bfl(g0.z), a0[4]); a0[5] = fmaf(w0, bfh(g0.z), a0[5]);
        a0[6] = fmaf(w0, bfl(g0.w), a0[6]); a0[7] = fmaf(w0, bfh(g0.w), a0[7]);
        a1[0] = fmaf(w1, bfl(g1.x), a1[0]); a1[1] = fmaf(w1, bfh(g1.x), a1[1]);
        a1[2] = fmaf(w1, bfl(g1.y), a1[2]); a1[3] = fmaf(w1, bfh(g1.y), a1[3]);
        a1[4] = fmaf(w1, bfl(g1.z), a1[4]); a1[5] = fmaf(w1, bfh(g1.z), a1[5]);
        a1[6] = fmaf(w1, bfl(g1.w), a1[6]); a1[7] = fmaf(w1, bfh(g1.w), a1[7]);
        a2[0] = fmaf(w2, bfl(g2.x), a2[0]); a2[1] = fmaf(w2, bfh(g2.x), a2[1]);
        a2[2] = fmaf(w2, bfl(g2.y), a2[2]); a2[3] = fmaf(w2, bfh(g2.y), a2[3]);
        a2[4] = fmaf(w2, bfl(g2.z), a2[4]); a2[5] = fmaf(w2, bfh(g2.z), a2[5]);
        a2[6] = fmaf(w2, bfl(g2.w), a2[6]); a2[7] = fmaf(w2, bfh(g2.w), a2[7]);
        a3[0] = fmaf(w3, bfl(g3.x), a3[0]); a3[1] = fmaf(w3, bfh(g3.x), a3[1]);
        a3[2] = fmaf(w3, bfl(g3.y), a3[2]); a3[3] = fmaf(w3, bfh(g3.y), a3[3]);
        a3[4] = fmaf(w3, bfl(g3.z), a3[4]); a3[5] = fmaf(w3, bfh(g3.z), a3[5]);
        a3[6] = fmaf(w3, bfl(g3.w), a3[6]); a3[7] = fmaf(w3, bfh(g3.w), a3[7]);
    }
    for (; e < e1; ++e) {
        int s = csr[e];
        uint4 g = Hb4[(size_t)s * 16 + lane];
        float w = dn * dis[s];
        a0[0] = fmaf(w, bfl(g.x), a0[0]); a0[1] = fmaf(w, bfh(g.x), a0[1]);
        a0[2] = fmaf(w, bfl(g.y), a0[2]); a0[3] = fmaf(w, bfh(g.y), a0[3]);
        a0[4] = fmaf(w, bfl(g.z), a0[4]); a0[5] = fmaf(w, bfh(g.z), a0[5]);
        a0[6] = fmaf(w, bfl(g.w), a0[6]); a0[7] = fmaf(w, bfh(g.w), a0[7]);
    }

    float4 b0 = ((const float4*)bias)[lane * 2];
    float4 b1v = ((const float4*)bias)[lane * 2 + 1];
    float r[8];
    r[0] = fmaxf(a0[0] + a1[0] + a2[0] + a3[0] + b0.x, 0.f);
    r[1] = fmaxf(a0[1] + a1[1] + a2[1] + a3[1] + b0.y, 0.f);
    r[2] = fmaxf(a0[2] + a1[2] + a2[2] + a3[2] + b0.z, 0.f);
    r[3] = fmaxf(a0[3] + a1[3] + a2[3] + a3[3] + b0.w, 0.f);
    r[4] = fmaxf(a0[4] + a1[4] + a2[4] + a3[4] + b1v.x, 0.f);
    r[5] = fmaxf(a0[5] + a1[5] + a2[5] + a3[5] + b1v.y, 0.f);
    r[6] = fmaxf(a0[6] + a1[6] + a2[6] + a3[6] + b1v.z, 0.f);
    r[7] = fmaxf(a0[7] + a1[7] + a2[7] + a3[7] + b1v.w, 0.f);

    if (MODE == 2) {
        // --- fused layer-2 GEMM: G2[16x128] = A1[16x128] @ W2 ---
        unsigned short* sA = (unsigned short*)smem;          // 16 x 136
        unsigned short* sC = (unsigned short*)smem + 2176;   // 16 x 136
        uint4 av;
        av.x = (unsigned)f2bf(r[0]) | ((unsigned)f2bf(r[1]) << 16);
        av.y = (unsigned)f2bf(r[2]) | ((unsigned)f2bf(r[3]) << 16);
        av.z = (unsigned)f2bf(r[4]) | ((unsigned)f2bf(r[5]) << 16);
        av.w = (unsigned)f2bf(r[6]) | ((unsigned)f2bf(r[7]) << 16);
        *(uint4*)(sA + nl * 136 + lane * 8) = av;
        __syncthreads();

        int wid = threadIdx.x >> 6;
        int l64 = threadIdx.x & 63;
        int m   = l64 & 15;
        int q   = l64 >> 4;
        short8 af[4];
#pragma unroll
        for (int ks = 0; ks < 4; ++ks)
            af[ks] = *(const short8*)(sA + m * 136 + ks * 32 + q * 8);
        f32x4 acc[2];
        acc[0] = (f32x4){0.f, 0.f, 0.f, 0.f};
        acc[1] = (f32x4){0.f, 0.f, 0.f, 0.f};
#pragma unroll
        for (int ks = 0; ks < 4; ++ks) {
#pragma unroll
            for (int j = 0; j < 2; ++j) {
                int ct = wid * 2 + j;
                short8 bfrag = W2f[(ks * 8 + ct) * 64 + l64];
                acc[j] = __builtin_amdgcn_mfma_f32_16x16x32_bf16(af[ks], bfrag, acc[j], 0, 0, 0);
            }
        }
#pragma unroll
        for (int j = 0; j < 2; ++j) {
#pragma unroll
            for (int reg = 0; reg < 4; ++reg)
                sC[(q * 4 + reg) * 136 + (wid * 2 + j) * 16 + m] = f2bf(acc[j][reg]);
        }
        __syncthreads();
        {
            int t = threadIdx.x;
            int row = t >> 4, ch = t & 15;
            uint4 vv = *(const uint4*)((const unsigned char*)sC + row * 272 + ch * 16);
            out[(size_t)(blockIdx.x * 16 + row) * 16 + ch] = vv;
        }
    } else {
        // --- MODE 1: fused mean-pool accumulation ---
        float* sacc = (float*)smem;            // 16 x DIM f32
        int* sg = (int*)(smem + 16 * DIM * 4); // 16 ints
#pragma unroll
        for (int j = 0; j < 8; ++j) sacc[nl * DIM + lane * 8 + j] = r[j];
        if (lane == 0) sg[nl] = batch[node];
        __syncthreads();
        int c = threadIdx.x;
        if (c < DIM) {
            float acc = 0.f;
            int curg = sg[0];
#pragma unroll
            for (int n2 = 0; n2 < 16; ++n2) {
                int g = sg[n2];
                if (g != curg) {
                    atomicAdd(&pool[curg * DIM + c], acc);
                    acc = 0.f; curg = g;
                }
                acc += sacc[n2 * DIM + c];
            }
            atomicAdd(&pool[curg * DIM + c], acc);
        }
    }
}

// ---------------- Final FC: counts via binary search on sorted batch ------
__global__ void k_fc(const float* __restrict__ pool, const int* __restrict__ batch,
                     const float* __restrict__ Wfc, const float* __restrict__ bfc,
                     float* __restrict__ out) {
    int id = blockIdx.x * blockDim.x + threadIdx.x;
    if (id >= N_GRAPHS * OUTD) return;
    int g = id >> 4, o = id & 15;
    int lo = 0, hi = N_NODES;
    while (lo < hi) { int mid = (lo + hi) >> 1; if (batch[mid] < g) lo = mid + 1; else hi = mid; }
    int l0 = lo;
    lo = 0; hi = N_NODES;
    while (lo < hi) { int mid = (lo + hi) >> 1; if (batch[mid] < g + 1) lo = mid + 1; else hi = mid; }
    int cntg = lo - l0;
    float inv = 1.0f / fmaxf((float)cntg, 1.0f);
    float acc = bfc[o];
    const float* p = pool + g * DIM;
    for (int c = 0; c < DIM; ++c)
        acc = fmaf(p[c] * inv, Wfc[c * OUTD + o], acc);
    out[id] = acc;
}

// ---------------- launch ----------------

extern "C" void kernel_launch(void* const* d_in, const int* in_sizes, int n_in,
                              void* d_out, int out_size, void* d_ws, size_t ws_size,
                              hipStream_t stream) {
    const float* x    = (const float*)d_in[0];
    const int*   ei   = (const int*)d_in[1];
    const int*   batch= (const int*)d_in[2];
    const float* W1   = (const float*)d_in[3];
    const float* b1   = (const float*)d_in[4];
    const float* W2   = (const float*)d_in[5];
    const float* b2   = (const float*)d_in[6];
    const float* Wfc  = (const float*)d_in[7];
    const float* bfc  = (const float*)d_in[8];
    float* out = (float*)d_out;

    char* ws = (char*)d_ws;
    size_t off = 0;
    auto alloc = [&](size_t bytes) -> char* {
        char* p = ws + off;
        off = (off + bytes + 255) & ~(size_t)255;
        return p;
    };
    int*      bcnt     = (int*)     alloc((size_t)NBUCK * 4);
    int*      row_off  = (int*)     alloc((size_t)(N_NODES + 1) * 4);
    float*    dis      = (float*)   alloc((size_t)N_NODES * 4);
    unsigned short* csr= (unsigned short*)alloc((size_t)N_EDGES * 2);
    unsigned* barr     = (unsigned*)alloc((size_t)NBUCK * BSLOT * 4);
    float*    pool     = (float*)   alloc((size_t)N_GRAPHS * DIM * 4);
    unsigned* W2f      = (unsigned*)alloc((size_t)(DIM / 2) * DIM * 4);
    unsigned short* Hb = (unsigned short*)alloc((size_t)N_NODES * DIM * 2);
    unsigned short* Hb2= (unsigned short*)alloc((size_t)N_NODES * DIM * 2);

    const int* src = ei;
    const int* dst = ei + N_EDGES;

    k_init<<<1, 256, 0, stream>>>(bcnt, pool, W2, W2f);
    // fused: layer-1 GEMM (f32 -> bf16) runs concurrently with edge binning
    k_fused1<<<GEMMB + BIN_GRID, 256, 0, stream>>>(x, W1, Hb, N_NODES,
                                                   src, dst, bcnt, barr);
    // CSR finalize + dis + per-node src-sort (L2 gather-window locality)
    k_binB<<<NBUCK, 256, 0, stream>>>(barr, bcnt, row_off, dis, csr);

    int agg_grid = (N_NODES + 15) / 16;    // 3125
    // layer-1 agg + fused layer-2 GEMM: reads G1(Hb), writes G2(Hb2)
    k_agg<2><<<agg_grid, 256, 0, stream>>>((const uint4*)Hb, row_off, csr, dis, b1,
                                           (uint4*)Hb2, batch, pool, (const short8*)W2f);
    // layer-2 agg + fused mean-pool: reads G2(Hb2)
    k_agg<1><<<agg_grid, 256, 0, stream>>>((const uint4*)Hb2, row_off, csr, dis, b2,
                                           nullptr, batch, pool, nullptr);
    k_fc<<<(N_GRAPHS * OUTD + 255) / 256, 256, 0, stream>>>(pool, batch, Wfc, bfc, out);
}

// Round 6
// 208.674 us; speedup vs baseline: 1.1484x; 1.1484x over previous
//
#include <hip/hip_runtime.h>
#include <math.h>

#define N_NODES 50000
#define N_EDGES 800000
#define N_GRAPHS 64
#define DIM 128
#define OUTD 16

// bucketed CSR build: 256 nodes per bucket, STATIC bucket regions
#define BSHIFT 8
#define BNODES 256
#define NBUCK ((N_NODES + BNODES - 1) / BNODES)   // 196
#define TILE 2048                                  // edges per binning block
#define RCAP 8192                                  // LDS stage capacity (entries)
#define BSLOT 4864                                 // static region (mean 4096 + 12 sigma)
#define GEMMB 256                                  // persistent gemm blocks
#define BIN_GRID ((N_EDGES + TILE - 1) / TILE)     // 391

typedef __attribute__((ext_vector_type(8))) short short8;
typedef __attribute__((ext_vector_type(4))) float f32x4;

// ---- bf16 helpers (round-to-nearest-even; values are finite) ----
static __device__ __forceinline__ unsigned short f2bf(float f) {
    unsigned u = __float_as_uint(f);
    u += 0x7fffu + ((u >> 16) & 1u);
    return (unsigned short)(u >> 16);
}
static __device__ __forceinline__ float bfl(unsigned u) {
    return __uint_as_float(u << 16);
}
static __device__ __forceinline__ float bfh(unsigned u) {
    return __uint_as_float(u & 0xffff0000u);
}

// ---------------- init: zero bucket counts + pool; preconvert W2 ----------
// W2f layout = gemm fragment order: uint[((kstep*8+ct)*64 + quad*16+(n&15))*4 + jw]
// holding bf16(W2[k][n]) | bf16(W2[k+1][n])<<16 for k=2*kp.
__global__ __launch_bounds__(256) void k_init(int* __restrict__ bcnt,
                                              float* __restrict__ pool,
                                              const float* __restrict__ W2,
                                              unsigned* __restrict__ W2f) {
    int tid = threadIdx.x;
    if (tid < NBUCK) bcnt[tid] = 0;
    for (int i = tid; i < N_GRAPHS * DIM; i += 256) pool[i] = 0.f;
    for (int idx = tid; idx < (DIM / 2) * DIM; idx += 256) {
        int kp = idx >> 7;          // 0..63
        int n  = idx & 127;
        int k  = kp * 2;
        int kstep = kp >> 4;
        int quad  = (kp >> 2) & 3;
        int jw    = kp & 3;
        int ct    = n >> 4;
        unsigned vlo = f2bf(W2[(size_t)k * DIM + n]);
        unsigned vhi = f2bf(W2[(size_t)(k + 1) * DIM + n]);
        W2f[(((kstep * 8 + ct) * 64) + quad * 16 + (n & 15)) * 4 + jw] = vlo | (vhi << 16);
    }
}

// ---------------- shared GEMM body (W in LDS, MFMA, LDS C-stage) ----------
template <int BF16IN>
static __device__ __forceinline__ void gemm_body(const void* __restrict__ Av,
                                                 const float* __restrict__ Wg,
                                                 unsigned short* __restrict__ C,
                                                 int nrows,
                                                 unsigned* smemW, unsigned* smemC,
                                                 int tile0, int tstride) {
    unsigned* Wl = smemW;
    {
        int t = threadIdx.x;
        int p = t & 63;
        int kp = p * 2;
        int n0 = (t >> 6) * 32;
        int kstep = kp >> 5;
        int quad = (kp >> 3) & 3;
        int jw = (kp & 7) >> 1;
        const float* r0 = Wg + (size_t)kp * DIM;
        const float* r1 = r0 + DIM;
        int rot = (p >> 2) & 7;
#pragma unroll
        for (int i4 = 0; i4 < 8; ++i4) {
            int nb = ((i4 + rot) & 7) * 4;
            int n = n0 + nb;
            float4 lo = *(const float4*)(r0 + n);
            float4 hi = *(const float4*)(r1 + n);
            const float* lp = &lo.x;
            const float* hp = &hi.x;
#pragma unroll
            for (int ii = 0; ii < 4; ++ii) {
                int nn = n + ii;
                int ct = nn >> 4;
                int l  = quad * 16 + (nn & 15);
                unsigned vlo = f2bf(lp[ii]);
                unsigned vhi = f2bf(hp[ii]);
                Wl[(((kstep * 8 + ct) * 64) + l) * 4 + jw] = vlo | (vhi << 16);
            }
        }
    }
    __syncthreads();

    int wid  = threadIdx.x >> 6;
    int lane = threadIdx.x & 63;
    int m    = lane & 15;
    int quad = lane >> 4;
    const short8* Wf = (const short8*)Wl;
    unsigned short* cs = (unsigned short*)smemC + wid * 4352;  // 32 rows x 136 ushorts
    const unsigned char* cb = (const unsigned char*)smemC + wid * 8704;

    int ntiles = (nrows + 127) / 128;
    for (int tile = tile0; tile < ntiles; tile += tstride) {
        int row0 = tile * 128 + wid * 32;
        if (row0 >= nrows) continue;

        int rA = row0 + m;      if (rA >= nrows) rA = nrows - 1;
        int rB = row0 + 16 + m; if (rB >= nrows) rB = nrows - 1;

        short8 af0[4], af1[4];
        if (BF16IN) {
            const unsigned short* arowA = (const unsigned short*)Av + (size_t)rA * DIM + quad * 8;
            const unsigned short* arowB = (const unsigned short*)Av + (size_t)rB * DIM + quad * 8;
#pragma unroll
            for (int ks = 0; ks < 4; ++ks) {
                af0[ks] = *(const short8*)(arowA + ks * 32);
                af1[ks] = *(const short8*)(arowB + ks * 32);
            }
        } else {
            const float* arowA = (const float*)Av + (size_t)rA * DIM + quad * 8;
            const float* arowB = (const float*)Av + (size_t)rB * DIM + quad * 8;
#pragma unroll
            for (int ks = 0; ks < 4; ++ks) {
                float4 lo = *(const float4*)(arowA + ks * 32);
                float4 hi = *(const float4*)(arowA + ks * 32 + 4);
                short8 f;
                f[0] = (short)f2bf(lo.x); f[1] = (short)f2bf(lo.y);
                f[2] = (short)f2bf(lo.z); f[3] = (short)f2bf(lo.w);
                f[4] = (short)f2bf(hi.x); f[5] = (short)f2bf(hi.y);
                f[6] = (short)f2bf(hi.z); f[7] = (short)f2bf(hi.w);
                af0[ks] = f;
                lo = *(const float4*)(arowB + ks * 32);
                hi = *(const float4*)(arowB + ks * 32 + 4);
                f[0] = (short)f2bf(lo.x); f[1] = (short)f2bf(lo.y);
                f[2] = (short)f2bf(lo.z); f[3] = (short)f2bf(lo.w);
                f[4] = (short)f2bf(hi.x); f[5] = (short)f2bf(hi.y);
                f[6] = (short)f2bf(hi.z); f[7] = (short)f2bf(hi.w);
                af1[ks] = f;
            }
        }

        f32x4 acc0[8], acc1[8];
#pragma unroll
        for (int ct = 0; ct < 8; ++ct) {
            acc0[ct] = (f32x4){0.f, 0.f, 0.f, 0.f};
            acc1[ct] = (f32x4){0.f, 0.f, 0.f, 0.f};
        }

#pragma unroll
        for (int ks = 0; ks < 4; ++ks) {
#pragma unroll
            for (int ct = 0; ct < 8; ++ct) {
                short8 bfrag = Wf[(ks * 8 + ct) * 64 + lane];
                acc0[ct] = __builtin_amdgcn_mfma_f32_16x16x32_bf16(af0[ks], bfrag, acc0[ct], 0, 0, 0);
                acc1[ct] = __builtin_amdgcn_mfma_f32_16x16x32_bf16(af1[ks], bfrag, acc1[ct], 0, 0, 0);
            }
        }

#pragma unroll
        for (int ct = 0; ct < 8; ++ct) {
#pragma unroll
            for (int reg = 0; reg < 4; ++reg) {
                cs[(quad * 4 + reg) * 136 + ct * 16 + m]      = f2bf(acc0[ct][reg]);
                cs[(16 + quad * 4 + reg) * 136 + ct * 16 + m] = f2bf(acc1[ct][reg]);
            }
        }
#pragma unroll
        for (int i = 0; i < 8; ++i) {
            int rg = i * 4 + quad;
            int r = row0 + rg;
            if (r < nrows) {
                uint4 vv = *(const uint4*)(cb + rg * 272 + m * 16);
                *((uint4*)(C + (size_t)r * DIM) + m) = vv;
            }
        }
    }
}

// ---------------- fused layer-1 GEMM + binA (independent work) ------------
__global__ __launch_bounds__(256) void k_fused1(const float* __restrict__ A,
                                                const float* __restrict__ Wg,
                                                unsigned short* __restrict__ C,
                                                int nrows,
                                                const int* __restrict__ src,
                                                const int* __restrict__ dstp,
                                                int* __restrict__ bcnt,
                                                unsigned* __restrict__ bucket_arr) {
    __shared__ unsigned smemW[32768 / 4];
    __shared__ unsigned smemC[34816 / 4];
    if (blockIdx.x >= GEMMB) {
        int* cnt  = (int*)smemW;
        int* base = cnt + NBUCK;
        int tile0 = (blockIdx.x - GEMMB) * TILE;
        for (int i = threadIdx.x; i < NBUCK; i += 256) cnt[i] = 0;
        __syncthreads();
#pragma unroll
        for (int j = 0; j < TILE / 512; ++j) {
            int e = tile0 + j * 512 + threadIdx.x * 2;
            if (e < N_EDGES) {
                int2 d = *(const int2*)(dstp + e);
                atomicAdd(&cnt[d.x >> BSHIFT], 1);
                atomicAdd(&cnt[d.y >> BSHIFT], 1);
            }
        }
        __syncthreads();
        for (int i = threadIdx.x; i < NBUCK; i += 256) {
            int c = cnt[i];
            base[i] = i * BSLOT + (c ? atomicAdd(&bcnt[i], c) : 0);
            cnt[i] = 0;   // reuse as local cursor
        }
        __syncthreads();
#pragma unroll
        for (int j = 0; j < TILE / 512; ++j) {
            int e = tile0 + j * 512 + threadIdx.x * 2;
            if (e < N_EDGES) {
                int2 s = *(const int2*)(src + e);
                int2 d = *(const int2*)(dstp + e);
                int b0 = d.x >> BSHIFT, b1 = d.y >> BSHIFT;
                int p0 = base[b0] + atomicAdd(&cnt[b0], 1);
                bucket_arr[p0] = (unsigned)s.x | ((unsigned)(d.x & 255) << 16);
                int p1 = base[b1] + atomicAdd(&cnt[b1], 1);
                bucket_arr[p1] = (unsigned)s.y | ((unsigned)(d.y & 255) << 16);
            }
        }
        return;
    }
    gemm_body<0>(A, Wg, C, nrows, smemW, smemC, blockIdx.x, GEMMB);
}

// ---------------- Pass B: bases scan + fine scatter + degree/rowoff/dis ----
// (R0-proven version; src-sort removed — it cost 45us in binB for ~4us agg gain)
__global__ __launch_bounds__(256) void k_binB(const unsigned* __restrict__ barr,
                                              const int* __restrict__ bcnt,
                                              int* __restrict__ row_off,
                                              float* __restrict__ dis,
                                              unsigned short* __restrict__ csr) {
    __shared__ unsigned raw[RCAP];
    __shared__ unsigned short stage[RCAP];
    __shared__ int hist[BNODES];
    __shared__ int scn[BNODES];
    __shared__ int borig[256], bscan[256];
    int tid = threadIdx.x;
    int b = blockIdx.x;
    int n0 = b << BSHIFT;

    int cv = (tid < NBUCK) ? bcnt[tid] : 0;
    borig[tid] = cv;
    bscan[tid] = cv;
    __syncthreads();
    for (int off = 1; off < 256; off <<= 1) {
        int t = (tid >= off) ? bscan[tid - off] : 0;
        __syncthreads();
        bscan[tid] += t;
        __syncthreads();
    }
    int rbase = bscan[b] - borig[b];
    int len = borig[b];
    const unsigned* bin = barr + (size_t)b * BSLOT;

    hist[tid] = 0;
    __syncthreads();
    for (int i = tid; i < len; i += 256) {
        unsigned ed = bin[i];
        if (i < RCAP) raw[i] = ed;
        atomicAdd(&hist[ed >> 16], 1);
    }
    __syncthreads();
    int v = hist[tid];
    scn[tid] = v;
    __syncthreads();
    for (int off = 1; off < 256; off <<= 1) {
        int t = (tid >= off) ? scn[tid - off] : 0;
        __syncthreads();
        scn[tid] += t;
        __syncthreads();
    }
    int excl = scn[tid] - v;
    int n = n0 + tid;
    if (n < N_NODES) {
        row_off[n] = rbase + excl;
        dis[n] = rsqrtf((float)(v + 1));   // +1 = self-loop
    }
    if (b == NBUCK - 1 && tid == 0) row_off[N_NODES] = N_EDGES;
    hist[tid] = excl;   // reuse as cursor
    __syncthreads();
    for (int i = tid; i < len; i += 256) {
        unsigned ed = (i < RCAP) ? raw[i] : bin[i];
        int p = atomicAdd(&hist[ed >> 16], 1);
        unsigned short sv = (unsigned short)(ed & 0xffffu);
        if (p < RCAP) stage[p] = sv;
        else csr[rbase + p] = sv;
    }
    __syncthreads();
    int lim = min(len, RCAP);
    for (int i = tid; i < lim; i += 256)
        csr[rbase + i] = stage[i];
}

// ---------------- Aggregation: TWO HALF-ROW PHASES ----------------
// Per phase only one 128B line per source row is touched -> instantaneous
// cacheable footprint 6.4MB (vs 12.8MB) -> higher per-XCD L2 hit rate ->
// lower average gather latency (the agg is latency-bound, ~36 outstanding
// lines/CU measured). Line count per edge unchanged (2 total).
// Phase results land in an LDS f32 stage (16x128), biased+relu'd.
static __device__ __forceinline__ void half_pass(const uint2* __restrict__ H2,
                                                 const unsigned short* __restrict__ csr,
                                                 const float* __restrict__ dis,
                                                 const float* __restrict__ bias,
                                                 float* __restrict__ strow,
                                                 int node, int eBeg, int e1,
                                                 int lane, float dn, float wself,
                                                 int ofs) {
    float a0[4], a1[4], a2[4], a3[4];
    uint2 hp = H2[(size_t)node * 32 + ofs + lane];
    a0[0] = wself * bfl(hp.x); a0[1] = wself * bfh(hp.x);
    a0[2] = wself * bfl(hp.y); a0[3] = wself * bfh(hp.y);
#pragma unroll
    for (int j = 0; j < 4; ++j) { a1[j] = 0.f; a2[j] = 0.f; a3[j] = 0.f; }

    int e = eBeg;
    for (; e + 4 <= e1; e += 4) {
        int s0 = csr[e];     int s1 = csr[e + 1];
        int s2 = csr[e + 2]; int s3 = csr[e + 3];
        uint2 g0 = H2[(size_t)s0 * 32 + ofs + lane];
        uint2 g1 = H2[(size_t)s1 * 32 + ofs + lane];
        uint2 g2 = H2[(size_t)s2 * 32 + ofs + lane];
        uint2 g3 = H2[(size_t)s3 * 32 + ofs + lane];
        float w0 = dn * dis[s0], w1 = dn * dis[s1];
        float w2 = dn * dis[s2], w3 = dn * dis[s3];
        a0[0] = fmaf(w0, bfl(g0.x), a0[0]); a0[1] = fmaf(w0, bfh(g0.x), a0[1]);
        a0[2] = fmaf(w0, bfl(g0.y), a0[2]); a0[3] = fmaf(w0, bfh(g0.y), a0[3]);
        a1[0] = fmaf(w1, bfl(g1.x), a1[0]); a1[1] = fmaf(w1, bfh(g1.x), a1[1]);
        a1[2] = fmaf(w1, bfl(g1.y), a1[2]); a1[3] = fmaf(w1, bfh(g1.y), a1[3]);
        a2[0] = fmaf(w2, bfl(g2.x), a2[0]); a2[1] = fmaf(w2, bfh(g2.x), a2[1]);
        a2[2] = fmaf(w2, bfl(g2.y), a2[2]); a2[3] = fmaf(w2, bfh(g2.y), a2[3]);
        a3[0] = fmaf(w3, bfl(g3.x), a3[0]); a3[1] = fmaf(w3, bfh(g3.x), a3[1]);
        a3[2] = fmaf(w3, bfl(g3.y), a3[2]); a3[3] = fmaf(w3, bfh(g3.y), a3[3]);
    }
    for (; e < e1; ++e) {
        int s = csr[e];
        uint2 g = H2[(size_t)s * 32 + ofs + lane];
        float w = dn * dis[s];
        a0[0] = fmaf(w, bfl(g.x), a0[0]); a0[1] = fmaf(w, bfh(g.x), a0[1]);
        a0[2] = fmaf(w, bfl(g.y), a0[2]); a0[3] = fmaf(w, bfh(g.y), a0[3]);
    }

    float4 bb = ((const float4*)bias)[ofs + lane];
    float* sp = strow + (ofs + lane) * 4;
    sp[0] = fmaxf(a0[0] + a1[0] + a2[0] + a3[0] + bb.x, 0.f);
    sp[1] = fmaxf(a0[1] + a1[1] + a2[1] + a3[1] + bb.y, 0.f);
    sp[2] = fmaxf(a0[2] + a1[2] + a2[2] + a3[2] + bb.z, 0.f);
    sp[3] = fmaxf(a0[3] + a1[3] + a2[3] + a3[3] + bb.w, 0.f);
}

// MODE==2 (layer 1): fuse layer-2 GEMM. MODE==1 (layer 2): fuse mean-pool.
template <int MODE>
__global__ __launch_bounds__(256) void k_agg(const uint4* __restrict__ Hb4,
                                             const int* __restrict__ row_off,
                                             const unsigned short* __restrict__ csr,
                                             const float* __restrict__ dis,
                                             const float* __restrict__ bias,
                                             uint4* __restrict__ out,
                                             const int* __restrict__ batch,
                                             float* __restrict__ pool,
                                             const short8* __restrict__ W2f) {
    __shared__ unsigned char smem[8768];
    float* stage = (float*)smem;                 // 16 x 128 f32 (8192 B)
    const uint2* H2 = (const uint2*)Hb4;
    int lane = threadIdx.x & 15;
    int nl   = threadIdx.x >> 4;      // node-local 0..15
    int node = blockIdx.x * 16 + nl;  // grid exact: 3125*16 = 50000

    int* sg = (int*)(smem + 8192);
    if (MODE == 1 && lane == 0) sg[nl] = batch[node];

    float dn = dis[node];
    float wself = dn * dn;
    int eBeg = row_off[node], e1 = row_off[node + 1];
    float* strow = stage + nl * 128;

    half_pass(H2, csr, dis, bias, strow, node, eBeg, e1, lane, dn, wself, 0);
    half_pass(H2, csr, dis, bias, strow, node, eBeg, e1, lane, dn, wself, 16);
    __syncthreads();

    if (MODE == 2) {
        // --- fused layer-2 GEMM: G2[16x128] = A1[16x128] @ W2 ---
        float r[8];
#pragma unroll
        for (int j = 0; j < 8; ++j) r[j] = stage[nl * 128 + lane * 8 + j];
        uint4 av;
        av.x = (unsigned)f2bf(r[0]) | ((unsigned)f2bf(r[1]) << 16);
        av.y = (unsigned)f2bf(r[2]) | ((unsigned)f2bf(r[3]) << 16);
        av.z = (unsigned)f2bf(r[4]) | ((unsigned)f2bf(r[5]) << 16);
        av.w = (unsigned)f2bf(r[6]) | ((unsigned)f2bf(r[7]) << 16);
        __syncthreads();   // all stage reads done before sA overwrite
        unsigned short* sA = (unsigned short*)smem;          // 16 x 136
        unsigned short* sC = (unsigned short*)smem + 2176;   // 16 x 136
        *(uint4*)(sA + nl * 136 + lane * 8) = av;
        __syncthreads();

        int wid = threadIdx.x >> 6;
        int l64 = threadIdx.x & 63;
        int m   = l64 & 15;
        int q   = l64 >> 4;
        short8 af[4];
#pragma unroll
        for (int ks = 0; ks < 4; ++ks)
            af[ks] = *(const short8*)(sA + m * 136 + ks * 32 + q * 8);
        f32x4 acc[2];
        acc[0] = (f32x4){0.f, 0.f, 0.f, 0.f};
        acc[1] = (f32x4){0.f, 0.f, 0.f, 0.f};
#pragma unroll
        for (int ks = 0; ks < 4; ++ks) {
#pragma unroll
            for (int j = 0; j < 2; ++j) {
                int ct = wid * 2 + j;
                short8 bfrag = W2f[(ks * 8 + ct) * 64 + l64];
                acc[j] = __builtin_amdgcn_mfma_f32_16x16x32_bf16(af[ks], bfrag, acc[j], 0, 0, 0);
            }
        }
#pragma unroll
        for (int j = 0; j < 2; ++j) {
#pragma unroll
            for (int reg = 0; reg < 4; ++reg)
                sC[(q * 4 + reg) * 136 + (wid * 2 + j) * 16 + m] = f2bf(acc[j][reg]);
        }
        __syncthreads();
        {
            int t = threadIdx.x;
            int row = t >> 4, ch = t & 15;
            uint4 vv = *(const uint4*)((const unsigned char*)sC + row * 272 + ch * 16);
            out[(size_t)(blockIdx.x * 16 + row) * 16 + ch] = vv;
        }
    } else {
        // --- MODE 1: fused mean-pool accumulation (stage already relu+bias) ---
        int c = threadIdx.x;
        if (c < DIM) {
            float acc = 0.f;
            int curg = sg[0];
#pragma unroll
            for (int n2 = 0; n2 < 16; ++n2) {
                int g = sg[n2];
                if (g != curg) {
                    atomicAdd(&pool[curg * DIM + c], acc);
                    acc = 0.f; curg = g;
                }
                acc += stage[n2 * 128 + c];
            }
            atomicAdd(&pool[curg * DIM + c], acc);
        }
    }
}

// ---------------- Final FC: counts via binary search on sorted batch ------
__global__ void k_fc(const float* __restrict__ pool, const int* __restrict__ batch,
                     const float* __restrict__ Wfc, const float* __restrict__ bfc,
                     float* __restrict__ out) {
    int id = blockIdx.x * blockDim.x + threadIdx.x;
    if (id >= N_GRAPHS * OUTD) return;
    int g = id >> 4, o = id & 15;
    int lo = 0, hi = N_NODES;
    while (lo < hi) { int mid = (lo + hi) >> 1; if (batch[mid] < g) lo = mid + 1; else hi = mid; }
    int l0 = lo;
    lo = 0; hi = N_NODES;
    while (lo < hi) { int mid = (lo + hi) >> 1; if (batch[mid] < g + 1) lo = mid + 1; else hi = mid; }
    int cntg = lo - l0;
    float inv = 1.0f / fmaxf((float)cntg, 1.0f);
    float acc = bfc[o];
    const float* p = pool + g * DIM;
    for (int c = 0; c < DIM; ++c)
        acc = fmaf(p[c] * inv, Wfc[c * OUTD + o], acc);
    out[id] = acc;
}

// ---------------- launch ----------------

extern "C" void kernel_launch(void* const* d_in, const int* in_sizes, int n_in,
                              void* d_out, int out_size, void* d_ws, size_t ws_size,
                              hipStream_t stream) {
    const float* x    = (const float*)d_in[0];
    const int*   ei   = (const int*)d_in[1];
    const int*   batch= (const int*)d_in[2];
    const float* W1   = (const float*)d_in[3];
    const float* b1   = (const float*)d_in[4];
    const float* W2   = (const float*)d_in[5];
    const float* b2   = (const float*)d_in[6];
    const float* Wfc  = (const float*)d_in[7];
    const float* bfc  = (const float*)d_in[8];
    float* out = (float*)d_out;

    char* ws = (char*)d_ws;
    size_t off = 0;
    auto alloc = [&](size_t bytes) -> char* {
        char* p = ws + off;
        off = (off + bytes + 255) & ~(size_t)255;
        return p;
    };
    int*      bcnt     = (int*)     alloc((size_t)NBUCK * 4);
    int*      row_off  = (int*)     alloc((size_t)(N_NODES + 1) * 4);
    float*    dis      = (float*)   alloc((size_t)N_NODES * 4);
    unsigned short* csr= (unsigned short*)alloc((size_t)N_EDGES * 2);
    unsigned* barr     = (unsigned*)alloc((size_t)NBUCK * BSLOT * 4);
    float*    pool     = (float*)   alloc((size_t)N_GRAPHS * DIM * 4);
    unsigned* W2f      = (unsigned*)alloc((size_t)(DIM / 2) * DIM * 4);
    unsigned short* Hb = (unsigned short*)alloc((size_t)N_NODES * DIM * 2);
    unsigned short* Hb2= (unsigned short*)alloc((size_t)N_NODES * DIM * 2);

    const int* src = ei;
    const int* dst = ei + N_EDGES;

    k_init<<<1, 256, 0, stream>>>(bcnt, pool, W2, W2f);
    // fused: layer-1 GEMM (f32 -> bf16) runs concurrently with edge binning
    k_fused1<<<GEMMB + BIN_GRID, 256, 0, stream>>>(x, W1, Hb, N_NODES,
                                                   src, dst, bcnt, barr);
    k_binB<<<NBUCK, 256, 0, stream>>>(barr, bcnt, row_off, dis, csr);

    int agg_grid = (N_NODES + 15) / 16;    // 3125
    // layer-1 agg + fused layer-2 GEMM: reads G1(Hb), writes G2(Hb2)
    k_agg<2><<<agg_grid, 256, 0, stream>>>((const uint4*)Hb, row_off, csr, dis, b1,
                                           (uint4*)Hb2, batch, pool, (const short8*)W2f);
    // layer-2 agg + fused mean-pool: reads G2(Hb2)
    k_agg<1><<<agg_grid, 256, 0, stream>>>((const uint4*)Hb2, row_off, csr, dis, b2,
                                           nullptr, batch, pool, nullptr);
    k_fc<<<(N_GRAPHS * OUTD + 255) / 256, 256, 0, stream>>>(pool, batch, Wfc, bfc, out);
}

// Round 7
// 202.426 us; speedup vs baseline: 1.1839x; 1.0309x over previous
//
#include <hip/hip_runtime.h>
#include <math.h>

#define N_NODES 50000
#define N_EDGES 800000
#define N_GRAPHS 64
#define DIM 128
#define OUTD 16

// bucketed CSR build: 256 nodes per bucket, STATIC bucket regions
#define BSHIFT 8
#define BNODES 256
#define NBUCK ((N_NODES + BNODES - 1) / BNODES)   // 196
#define TILE 2048                                  // edges per binning block
#define RCAP 8192                                  // LDS stage capacity (entries)
#define BSLOT 4864                                 // static region (mean 4096 + 12 sigma)
#define GEMMB 256                                  // persistent gemm blocks
#define BIN_GRID ((N_EDGES + TILE - 1) / TILE)     // 391

typedef __attribute__((ext_vector_type(8))) short short8;
typedef __attribute__((ext_vector_type(4))) float f32x4;

// ---- bf16 helpers (round-to-nearest-even; values are finite) ----
static __device__ __forceinline__ unsigned short f2bf(float f) {
    unsigned u = __float_as_uint(f);
    u += 0x7fffu + ((u >> 16) & 1u);
    return (unsigned short)(u >> 16);
}
static __device__ __forceinline__ float bfl(unsigned u) {
    return __uint_as_float(u << 16);
}
static __device__ __forceinline__ float bfh(unsigned u) {
    return __uint_as_float(u & 0xffff0000u);
}

// ---------------- shared GEMM body (W in LDS, MFMA, LDS C-stage) ----------
template <int BF16IN>
static __device__ __forceinline__ void gemm_body(const void* __restrict__ Av,
                                                 const float* __restrict__ Wg,
                                                 unsigned short* __restrict__ C,
                                                 int nrows,
                                                 unsigned* smemW, unsigned* smemC,
                                                 int tile0, int tstride) {
    unsigned* Wl = smemW;
    {
        int t = threadIdx.x;
        int p = t & 63;
        int kp = p * 2;
        int n0 = (t >> 6) * 32;
        int kstep = kp >> 5;
        int quad = (kp >> 3) & 3;
        int jw = (kp & 7) >> 1;
        const float* r0 = Wg + (size_t)kp * DIM;
        const float* r1 = r0 + DIM;
        int rot = (p >> 2) & 7;
#pragma unroll
        for (int i4 = 0; i4 < 8; ++i4) {
            int nb = ((i4 + rot) & 7) * 4;
            int n = n0 + nb;
            float4 lo = *(const float4*)(r0 + n);
            float4 hi = *(const float4*)(r1 + n);
            const float* lp = &lo.x;
            const float* hp = &hi.x;
#pragma unroll
            for (int ii = 0; ii < 4; ++ii) {
                int nn = n + ii;
                int ct = nn >> 4;
                int l  = quad * 16 + (nn & 15);
                unsigned vlo = f2bf(lp[ii]);
                unsigned vhi = f2bf(hp[ii]);
                Wl[(((kstep * 8 + ct) * 64) + l) * 4 + jw] = vlo | (vhi << 16);
            }
        }
    }
    __syncthreads();

    int wid  = threadIdx.x >> 6;
    int lane = threadIdx.x & 63;
    int m    = lane & 15;
    int quad = lane >> 4;
    const short8* Wf = (const short8*)Wl;
    unsigned short* cs = (unsigned short*)smemC + wid * 4352;  // 32 rows x 136 ushorts
    const unsigned char* cb = (const unsigned char*)smemC + wid * 8704;

    int ntiles = (nrows + 127) / 128;
    for (int tile = tile0; tile < ntiles; tile += tstride) {
        int row0 = tile * 128 + wid * 32;
        if (row0 >= nrows) continue;

        int rA = row0 + m;      if (rA >= nrows) rA = nrows - 1;
        int rB = row0 + 16 + m; if (rB >= nrows) rB = nrows - 1;

        short8 af0[4], af1[4];
        if (BF16IN) {
            const unsigned short* arowA = (const unsigned short*)Av + (size_t)rA * DIM + quad * 8;
            const unsigned short* arowB = (const unsigned short*)Av + (size_t)rB * DIM + quad * 8;
#pragma unroll
            for (int ks = 0; ks < 4; ++ks) {
                af0[ks] = *(const short8*)(arowA + ks * 32);
                af1[ks] = *(const short8*)(arowB + ks * 32);
            }
        } else {
            const float* arowA = (const float*)Av + (size_t)rA * DIM + quad * 8;
            const float* arowB = (const float*)Av + (size_t)rB * DIM + quad * 8;
#pragma unroll
            for (int ks = 0; ks < 4; ++ks) {
                float4 lo = *(const float4*)(arowA + ks * 32);
                float4 hi = *(const float4*)(arowA + ks * 32 + 4);
                short8 f;
                f[0] = (short)f2bf(lo.x); f[1] = (short)f2bf(lo.y);
                f[2] = (short)f2bf(lo.z); f[3] = (short)f2bf(lo.w);
                f[4] = (short)f2bf(hi.x); f[5] = (short)f2bf(hi.y);
                f[6] = (short)f2bf(hi.z); f[7] = (short)f2bf(hi.w);
                af0[ks] = f;
                lo = *(const float4*)(arowB + ks * 32);
                hi = *(const float4*)(arowB + ks * 32 + 4);
                f[0] = (short)f2bf(lo.x); f[1] = (short)f2bf(lo.y);
                f[2] = (short)f2bf(lo.z); f[3] = (short)f2bf(lo.w);
                f[4] = (short)f2bf(hi.x); f[5] = (short)f2bf(hi.y);
                f[6] = (short)f2bf(hi.z); f[7] = (short)f2bf(hi.w);
                af1[ks] = f;
            }
        }

        f32x4 acc0[8], acc1[8];
#pragma unroll
        for (int ct = 0; ct < 8; ++ct) {
            acc0[ct] = (f32x4){0.f, 0.f, 0.f, 0.f};
            acc1[ct] = (f32x4){0.f, 0.f, 0.f, 0.f};
        }

#pragma unroll
        for (int ks = 0; ks < 4; ++ks) {
#pragma unroll
            for (int ct = 0; ct < 8; ++ct) {
                short8 bfrag = Wf[(ks * 8 + ct) * 64 + lane];
                acc0[ct] = __builtin_amdgcn_mfma_f32_16x16x32_bf16(af0[ks], bfrag, acc0[ct], 0, 0, 0);
                acc1[ct] = __builtin_amdgcn_mfma_f32_16x16x32_bf16(af1[ks], bfrag, acc1[ct], 0, 0, 0);
            }
        }

#pragma unroll
        for (int ct = 0; ct < 8; ++ct) {
#pragma unroll
            for (int reg = 0; reg < 4; ++reg) {
                cs[(quad * 4 + reg) * 136 + ct * 16 + m]      = f2bf(acc0[ct][reg]);
                cs[(16 + quad * 4 + reg) * 136 + ct * 16 + m] = f2bf(acc1[ct][reg]);
            }
        }
#pragma unroll
        for (int i = 0; i < 8; ++i) {
            int rg = i * 4 + quad;
            int r = row0 + rg;
            if (r < nrows) {
                uint4 vv = *(const uint4*)(cb + rg * 272 + m * 16);
                *((uint4*)(C + (size_t)r * DIM) + m) = vv;
            }
        }
    }
}

// ---------------- fused layer-1 GEMM + binA (independent work) ------------
__global__ __launch_bounds__(256) void k_fused1(const float* __restrict__ A,
                                                const float* __restrict__ Wg,
                                                unsigned short* __restrict__ C,
                                                int nrows,
                                                const int* __restrict__ src,
                                                const int* __restrict__ dstp,
                                                int* __restrict__ bcnt,
                                                unsigned* __restrict__ bucket_arr) {
    __shared__ unsigned smemW[32768 / 4];
    __shared__ unsigned smemC[34816 / 4];
    if (blockIdx.x >= GEMMB) {
        int* cnt  = (int*)smemW;
        int* base = cnt + NBUCK;
        int tile0 = (blockIdx.x - GEMMB) * TILE;
        for (int i = threadIdx.x; i < NBUCK; i += 256) cnt[i] = 0;
        __syncthreads();
#pragma unroll
        for (int j = 0; j < TILE / 512; ++j) {
            int e = tile0 + j * 512 + threadIdx.x * 2;
            if (e < N_EDGES) {
                int2 d = *(const int2*)(dstp + e);
                atomicAdd(&cnt[d.x >> BSHIFT], 1);
                atomicAdd(&cnt[d.y >> BSHIFT], 1);
            }
        }
        __syncthreads();
        for (int i = threadIdx.x; i < NBUCK; i += 256) {
            int c = cnt[i];
            base[i] = i * BSLOT + (c ? atomicAdd(&bcnt[i], c) : 0);
            cnt[i] = 0;   // reuse as local cursor
        }
        __syncthreads();
#pragma unroll
        for (int j = 0; j < TILE / 512; ++j) {
            int e = tile0 + j * 512 + threadIdx.x * 2;
            if (e < N_EDGES) {
                int2 s = *(const int2*)(src + e);
                int2 d = *(const int2*)(dstp + e);
                int b0 = d.x >> BSHIFT, b1 = d.y >> BSHIFT;
                int p0 = base[b0] + atomicAdd(&cnt[b0], 1);
                bucket_arr[p0] = (unsigned)s.x | ((unsigned)(d.x & 255) << 16);
                int p1 = base[b1] + atomicAdd(&cnt[b1], 1);
                bucket_arr[p1] = (unsigned)s.y | ((unsigned)(d.y & 255) << 16);
            }
        }
        return;
    }
    gemm_body<0>(A, Wg, C, nrows, smemW, smemC, blockIdx.x, GEMMB);
}

// ---------------- Pass B: bases scan + fine scatter + degree/rowoff/dis ----
// Also absorbs the former k_init work (block 0): pool zero + W2 fragment
// preconversion. (bcnt zeroing moved to hipMemsetAsync.) One fewer dispatch.
__global__ __launch_bounds__(256) void k_binB(const unsigned* __restrict__ barr,
                                              const int* __restrict__ bcnt,
                                              int* __restrict__ row_off,
                                              float* __restrict__ dis,
                                              unsigned short* __restrict__ csr,
                                              const float* __restrict__ W2,
                                              float* __restrict__ pool,
                                              unsigned* __restrict__ W2f) {
    __shared__ unsigned raw[RCAP];
    __shared__ unsigned short stage[RCAP];
    __shared__ int hist[BNODES];
    __shared__ int scn[BNODES];
    __shared__ int borig[256], bscan[256];
    int tid = threadIdx.x;
    int b = blockIdx.x;
    int n0 = b << BSHIFT;

    // ---- folded k_init (block 0): zero pool, preconvert W2 -> fragment order
    if (b == 0) {
        for (int i = tid; i < N_GRAPHS * DIM; i += 256) pool[i] = 0.f;
        for (int idx = tid; idx < (DIM / 2) * DIM; idx += 256) {
            int kp = idx >> 7;          // 0..63
            int n  = idx & 127;
            int k  = kp * 2;
            int kstep = kp >> 4;
            int quad  = (kp >> 2) & 3;
            int jw    = kp & 3;
            int ct    = n >> 4;
            unsigned vlo = f2bf(W2[(size_t)k * DIM + n]);
            unsigned vhi = f2bf(W2[(size_t)(k + 1) * DIM + n]);
            W2f[(((kstep * 8 + ct) * 64) + quad * 16 + (n & 15)) * 4 + jw] = vlo | (vhi << 16);
        }
    }

    int cv = (tid < NBUCK) ? bcnt[tid] : 0;
    borig[tid] = cv;
    bscan[tid] = cv;
    __syncthreads();
    for (int off = 1; off < 256; off <<= 1) {
        int t = (tid >= off) ? bscan[tid - off] : 0;
        __syncthreads();
        bscan[tid] += t;
        __syncthreads();
    }
    int rbase = bscan[b] - borig[b];
    int len = borig[b];
    const unsigned* bin = barr + (size_t)b * BSLOT;

    hist[tid] = 0;
    __syncthreads();
    for (int i = tid; i < len; i += 256) {
        unsigned ed = bin[i];
        if (i < RCAP) raw[i] = ed;
        atomicAdd(&hist[ed >> 16], 1);
    }
    __syncthreads();
    int v = hist[tid];
    scn[tid] = v;
    __syncthreads();
    for (int off = 1; off < 256; off <<= 1) {
        int t = (tid >= off) ? scn[tid - off] : 0;
        __syncthreads();
        scn[tid] += t;
        __syncthreads();
    }
    int excl = scn[tid] - v;
    int n = n0 + tid;
    if (n < N_NODES) {
        row_off[n] = rbase + excl;
        dis[n] = rsqrtf((float)(v + 1));   // +1 = self-loop
    }
    if (b == NBUCK - 1 && tid == 0) row_off[N_NODES] = N_EDGES;
    hist[tid] = excl;   // reuse as cursor
    __syncthreads();
    for (int i = tid; i < len; i += 256) {
        unsigned ed = (i < RCAP) ? raw[i] : bin[i];
        int p = atomicAdd(&hist[ed >> 16], 1);
        unsigned short sv = (unsigned short)(ed & 0xffffu);
        if (p < RCAP) stage[p] = sv;
        else csr[rbase + p] = sv;
    }
    __syncthreads();
    int lim = min(len, RCAP);
    for (int i = tid; i < lim; i += 256)
        csr[rbase + i] = stage[i];
}

// ---------------- Aggregation (pull, bf16 gather) ----------------
// 16 lanes/node, 16 nodes/block, STATIC mapping, fat register accumulators
// (4 banks x 8) keep 4 gathers in flight — the proven R0 structure.
// MODE==2 (layer 1): R0 weighted gather (dis[s] per edge); fused layer-2
//   GEMM epilogue writes Hb2 rows PRE-SCALED by dis (sdS multiply, free).
// MODE==1 (layer 2): input rows pre-scaled -> inner loop is PURE ROW-ADDS
//   (no dis gather, no weight FMA); final scale by dn; fused mean-pool.
template <int MODE>
__global__ __launch_bounds__(256) void k_agg(const uint4* __restrict__ Hb4,
                                             const int* __restrict__ row_off,
                                             const unsigned short* __restrict__ csr,
                                             const float* __restrict__ dis,
                                             const float* __restrict__ bias,
                                             uint4* __restrict__ out,
                                             const int* __restrict__ batch,
                                             float* __restrict__ pool,
                                             const short8* __restrict__ W2f) {
    __shared__ unsigned char smem[8768];
    __shared__ float sdS[16];
    int lane = threadIdx.x & 15;
    int nl   = threadIdx.x >> 4;      // node-local 0..15
    int node = blockIdx.x * 16 + nl;  // grid exact: 3125*16 = 50000

    float dn = dis[node];
    if (lane == 0) sdS[nl] = dn;
    uint4 hp = Hb4[(size_t)node * 16 + lane];
    float a0[8], a1[8], a2[8], a3[8];
    if (MODE == 2) {
        float wself = dn * dn;
        a0[0] = wself * bfl(hp.x); a0[1] = wself * bfh(hp.x);
        a0[2] = wself * bfl(hp.y); a0[3] = wself * bfh(hp.y);
        a0[4] = wself * bfl(hp.z); a0[5] = wself * bfh(hp.z);
        a0[6] = wself * bfl(hp.w); a0[7] = wself * bfh(hp.w);
    } else {
        // rows pre-scaled by dis: self contribution = dn*(dn*H[n]) handled by
        // the final dn multiply; seed with the raw (pre-scaled) row.
        a0[0] = bfl(hp.x); a0[1] = bfh(hp.x);
        a0[2] = bfl(hp.y); a0[3] = bfh(hp.y);
        a0[4] = bfl(hp.z); a0[5] = bfh(hp.z);
        a0[6] = bfl(hp.w); a0[7] = bfh(hp.w);
    }
#pragma unroll
    for (int j = 0; j < 8; ++j) { a1[j] = 0.f; a2[j] = 0.f; a3[j] = 0.f; }

    int e = row_off[node], e1 = row_off[node + 1];
    if (MODE == 2) {
        for (; e + 4 <= e1; e += 4) {
            int s0 = csr[e];     int s1 = csr[e + 1];
            int s2 = csr[e + 2]; int s3 = csr[e + 3];
            uint4 g0 = Hb4[(size_t)s0 * 16 + lane];
            uint4 g1 = Hb4[(size_t)s1 * 16 + lane];
            uint4 g2 = Hb4[(size_t)s2 * 16 + lane];
            uint4 g3 = Hb4[(size_t)s3 * 16 + lane];
            float w0 = dn * dis[s0], w1 = dn * dis[s1];
            float w2 = dn * dis[s2], w3 = dn * dis[s3];
            a0[0] = fmaf(w0, bfl(g0.x), a0[0]); a0[1] = fmaf(w0, bfh(g0.x), a0[1]);
            a0[2] = fmaf(w0, bfl(g0.y), a0[2]); a0[3] = fmaf(w0, bfh(g0.y), a0[3]);
            a0[4] = fmaf(w0, bfl(g0.z), a0[4]); a0[5] = fmaf(w0, bfh(g0.z), a0[5]);
            a0[6] = fmaf(w0, bfl(g0.w), a0[6]); a0[7] = fmaf(w0, bfh(g0.w), a0[7]);
            a1[0] = fmaf(w1, bfl(g1.x), a1[0]); a1[1] = fmaf(w1, bfh(g1.x), a1[1]);
            a1[2] = fmaf(w1, bfl(g1.y), a1[2]); a1[3] = fmaf(w1, bfh(g1.y), a1[3]);
            a1[4] = fmaf(w1, bfl(g1.z), a1[4]); a1[5] = fmaf(w1, bfh(g1.z), a1[5]);
            a1[6] = fmaf(w1, bfl(g1.w), a1[6]); a1[7] = fmaf(w1, bfh(g1.w), a1[7]);
            a2[0] = fmaf(w2, bfl(g2.x), a2[0]); a2[1] = fmaf(w2, bfh(g2.x), a2[1]);
            a2[2] = fmaf(w2, bfl(g2.y), a2[2]); a2[3] = fmaf(w2, bfh(g2.y), a2[3]);
            a2[4] = fmaf(w2, bfl(g2.z), a2[4]); a2[5] = fmaf(w2, bfh(g2.z), a2[5]);
            a2[6] = fmaf(w2, bfl(g2.w), a2[6]); a2[7] = fmaf(w2, bfh(g2.w), a2[7]);
            a3[0] = fmaf(w3, bfl(g3.x), a3[0]); a3[1] = fmaf(w3, bfh(g3.x), a3[1]);
            a3[2] = fmaf(w3, bfl(g3.y), a3[2]); a3[3] = fmaf(w3, bfh(g3.y), a3[3]);
            a3[4] = fmaf(w3, bfl(g3.z), a3[4]); a3[5] = fmaf(w3, bfh(g3.z), a3[5]);
            a3[6] = fmaf(w3, bfl(g3.w), a3[6]); a3[7] = fmaf(w3, bfh(g3.w), a3[7]);
        }
        for (; e < e1; ++e) {
            int s = csr[e];
            uint4 g = Hb4[(size_t)s * 16 + lane];
            float w = dn * dis[s];
            a0[0] = fmaf(w, bfl(g.x), a0[0]); a0[1] = fmaf(w, bfh(g.x), a0[1]);
            a0[2] = fmaf(w, bfl(g.y), a0[2]); a0[3] = fmaf(w, bfh(g.y), a0[3]);
            a0[4] = fmaf(w, bfl(g.z), a0[4]); a0[5] = fmaf(w, bfh(g.z), a0[5]);
            a0[6] = fmaf(w, bfl(g.w), a0[6]); a0[7] = fmaf(w, bfh(g.w), a0[7]);
        }
    } else {
#define ACC8(A, g) do { \
        A[0] += bfl(g.x); A[1] += bfh(g.x); \
        A[2] += bfl(g.y); A[3] += bfh(g.y); \
        A[4] += bfl(g.z); A[5] += bfh(g.z); \
        A[6] += bfl(g.w); A[7] += bfh(g.w); \
    } while (0)
        for (; e + 4 <= e1; e += 4) {
            int s0 = csr[e];     int s1 = csr[e + 1];
            int s2 = csr[e + 2]; int s3 = csr[e + 3];
            uint4 g0 = Hb4[(size_t)s0 * 16 + lane];
            uint4 g1 = Hb4[(size_t)s1 * 16 + lane];
            uint4 g2 = Hb4[(size_t)s2 * 16 + lane];
            uint4 g3 = Hb4[(size_t)s3 * 16 + lane];
            ACC8(a0, g0); ACC8(a1, g1); ACC8(a2, g2); ACC8(a3, g3);
        }
        for (; e < e1; ++e) {
            int s = csr[e];
            uint4 g = Hb4[(size_t)s * 16 + lane];
            ACC8(a0, g);
        }
#undef ACC8
    }

    float4 b0 = ((const float4*)bias)[lane * 2];
    float4 b1v = ((const float4*)bias)[lane * 2 + 1];
    float r[8];
    if (MODE == 2) {
        r[0] = fmaxf(a0[0] + a1[0] + a2[0] + a3[0] + b0.x, 0.f);
        r[1] = fmaxf(a0[1] + a1[1] + a2[1] + a3[1] + b0.y, 0.f);
        r[2] = fmaxf(a0[2] + a1[2] + a2[2] + a3[2] + b0.z, 0.f);
        r[3] = fmaxf(a0[3] + a1[3] + a2[3] + a3[3] + b0.w, 0.f);
        r[4] = fmaxf(a0[4] + a1[4] + a2[4] + a3[4] + b1v.x, 0.f);
        r[5] = fmaxf(a0[5] + a1[5] + a2[5] + a3[5] + b1v.y, 0.f);
        r[6] = fmaxf(a0[6] + a1[6] + a2[6] + a3[6] + b1v.z, 0.f);
        r[7] = fmaxf(a0[7] + a1[7] + a2[7] + a3[7] + b1v.w, 0.f);
    } else {
        r[0] = fmaxf(fmaf(dn, a0[0] + a1[0] + a2[0] + a3[0], b0.x), 0.f);
        r[1] = fmaxf(fmaf(dn, a0[1] + a1[1] + a2[1] + a3[1], b0.y), 0.f);
        r[2] = fmaxf(fmaf(dn, a0[2] + a1[2] + a2[2] + a3[2], b0.z), 0.f);
        r[3] = fmaxf(fmaf(dn, a0[3] + a1[3] + a2[3] + a3[3], b0.w), 0.f);
        r[4] = fmaxf(fmaf(dn, a0[4] + a1[4] + a2[4] + a3[4], b1v.x), 0.f);
        r[5] = fmaxf(fmaf(dn, a0[5] + a1[5] + a2[5] + a3[5], b1v.y), 0.f);
        r[6] = fmaxf(fmaf(dn, a0[6] + a1[6] + a2[6] + a3[6], b1v.z), 0.f);
        r[7] = fmaxf(fmaf(dn, a0[7] + a1[7] + a2[7] + a3[7], b1v.w), 0.f);
    }

    if (MODE == 2) {
        // --- fused layer-2 GEMM: Hb2[16x128] = relu(A1)[16x128] @ W2,
        //     C rows scaled by dis at write (Hb2 comes out pre-scaled) ---
        unsigned short* sA = (unsigned short*)smem;          // 16 x 136
        unsigned short* sC = (unsigned short*)smem + 2176;   // 16 x 136
        uint4 av;
        av.x = (unsigned)f2bf(r[0]) | ((unsigned)f2bf(r[1]) << 16);
        av.y = (unsigned)f2bf(r[2]) | ((unsigned)f2bf(r[3]) << 16);
        av.z = (unsigned)f2bf(r[4]) | ((unsigned)f2bf(r[5]) << 16);
        av.w = (unsigned)f2bf(r[6]) | ((unsigned)f2bf(r[7]) << 16);
        *(uint4*)(sA + nl * 136 + lane * 8) = av;
        __syncthreads();

        int wid = threadIdx.x >> 6;
        int l64 = threadIdx.x & 63;
        int m   = l64 & 15;
        int q   = l64 >> 4;
        short8 af[4];
#pragma unroll
        for (int ks = 0; ks < 4; ++ks)
            af[ks] = *(const short8*)(sA + m * 136 + ks * 32 + q * 8);
        f32x4 acc[2];
        acc[0] = (f32x4){0.f, 0.f, 0.f, 0.f};
        acc[1] = (f32x4){0.f, 0.f, 0.f, 0.f};
#pragma unroll
        for (int ks = 0; ks < 4; ++ks) {
#pragma unroll
            for (int j = 0; j < 2; ++j) {
                int ct = wid * 2 + j;
                short8 bfrag = W2f[(ks * 8 + ct) * 64 + l64];
                acc[j] = __builtin_amdgcn_mfma_f32_16x16x32_bf16(af[ks], bfrag, acc[j], 0, 0, 0);
            }
        }
#pragma unroll
        for (int j = 0; j < 2; ++j) {
#pragma unroll
            for (int reg = 0; reg < 4; ++reg) {
                float sc = sdS[q * 4 + reg];   // C row q*4+reg -> local node
                sC[(q * 4 + reg) * 136 + (wid * 2 + j) * 16 + m] = f2bf(acc[j][reg] * sc);
            }
        }
        __syncthreads();
        {
            int t = threadIdx.x;
            int row = t >> 4, ch = t & 15;
            uint4 vv = *(const uint4*)((const unsigned char*)sC + row * 272 + ch * 16);
            out[(size_t)(blockIdx.x * 16 + row) * 16 + ch] = vv;
        }
    } else {
        // --- MODE 1: fused mean-pool accumulation ---
        float* sacc = (float*)smem;            // 16 x DIM f32
        int* sg = (int*)(smem + 16 * DIM * 4); // 16 ints
#pragma unroll
        for (int j = 0; j < 8; ++j) sacc[nl * DIM + lane * 8 + j] = r[j];
        if (lane == 0) sg[nl] = batch[node];
        __syncthreads();
        int c = threadIdx.x;
        if (c < DIM) {
            float acc = 0.f;
            int curg = sg[0];
#pragma unroll
            for (int n2 = 0; n2 < 16; ++n2) {
                int g = sg[n2];
                if (g != curg) {
                    atomicAdd(&pool[curg * DIM + c], acc);
                    acc = 0.f; curg = g;
                }
                acc += sacc[n2 * DIM + c];
            }
            atomicAdd(&pool[curg * DIM + c], acc);
        }
    }
}

// ---------------- Final FC: counts via binary search on sorted batch ------
__global__ void k_fc(const float* __restrict__ pool, const int* __restrict__ batch,
                     const float* __restrict__ Wfc, const float* __restrict__ bfc,
                     float* __restrict__ out) {
    int id = blockIdx.x * blockDim.x + threadIdx.x;
    if (id >= N_GRAPHS * OUTD) return;
    int g = id >> 4, o = id & 15;
    int lo = 0, hi = N_NODES;
    while (lo < hi) { int mid = (lo + hi) >> 1; if (batch[mid] < g) lo = mid + 1; else hi = mid; }
    int l0 = lo;
    lo = 0; hi = N_NODES;
    while (lo < hi) { int mid = (lo + hi) >> 1; if (batch[mid] < g + 1) lo = mid + 1; else hi = mid; }
    int cntg = lo - l0;
    float inv = 1.0f / fmaxf((float)cntg, 1.0f);
    float acc = bfc[o];
    const float* p = pool + g * DIM;
    for (int c = 0; c < DIM; ++c)
        acc = fmaf(p[c] * inv, Wfc[c * OUTD + o], acc);
    out[id] = acc;
}

// ---------------- launch ----------------

extern "C" void kernel_launch(void* const* d_in, const int* in_sizes, int n_in,
                              void* d_out, int out_size, void* d_ws, size_t ws_size,
                              hipStream_t stream) {
    const float* x    = (const float*)d_in[0];
    const int*   ei   = (const int*)d_in[1];
    const int*   batch= (const int*)d_in[2];
    const float* W1   = (const float*)d_in[3];
    const float* b1   = (const float*)d_in[4];
    const float* W2   = (const float*)d_in[5];
    const float* b2   = (const float*)d_in[6];
    const float* Wfc  = (const float*)d_in[7];
    const float* bfc  = (const float*)d_in[8];
    float* out = (float*)d_out;

    char* ws = (char*)d_ws;
    size_t off = 0;
    auto alloc = [&](size_t bytes) -> char* {
        char* p = ws + off;
        off = (off + bytes + 255) & ~(size_t)255;
        return p;
    };
    int*      bcnt     = (int*)     alloc((size_t)NBUCK * 4);
    int*      row_off  = (int*)     alloc((size_t)(N_NODES + 1) * 4);
    float*    dis      = (float*)   alloc((size_t)N_NODES * 4);
    unsigned short* csr= (unsigned short*)alloc((size_t)N_EDGES * 2);
    unsigned* barr     = (unsigned*)alloc((size_t)NBUCK * BSLOT * 4);
    float*    pool     = (float*)   alloc((size_t)N_GRAPHS * DIM * 4);
    unsigned* W2f      = (unsigned*)alloc((size_t)(DIM / 2) * DIM * 4);
    unsigned short* Hb = (unsigned short*)alloc((size_t)N_NODES * DIM * 2);
    unsigned short* Hb2= (unsigned short*)alloc((size_t)N_NODES * DIM * 2);

    const int* src = ei;
    const int* dst = ei + N_EDGES;

    // bcnt zero via async memset (replaces the serial k_init dispatch)
    hipMemsetAsync(bcnt, 0, (size_t)NBUCK * 4, stream);
    // fused: layer-1 GEMM (f32 -> bf16) runs concurrently with edge binning
    k_fused1<<<GEMMB + BIN_GRID, 256, 0, stream>>>(x, W1, Hb, N_NODES,
                                                   src, dst, bcnt, barr);
    // CSR finalize + dis; block 0 also zeroes pool + preconverts W2
    k_binB<<<NBUCK, 256, 0, stream>>>(barr, bcnt, row_off, dis, csr,
                                      W2, pool, W2f);

    int agg_grid = (N_NODES + 15) / 16;    // 3125
    // layer-1 agg (R0 weighted gather) + fused layer-2 GEMM; Hb2 pre-scaled
    k_agg<2><<<agg_grid, 256, 0, stream>>>((const uint4*)Hb, row_off, csr, dis, b1,
                                           (uint4*)Hb2, batch, pool, (const short8*)W2f);
    // layer-2 agg (pure row-adds, no per-edge dis) + fused mean-pool
    k_agg<1><<<agg_grid, 256, 0, stream>>>((const uint4*)Hb2, row_off, csr, dis, b2,
                                           nullptr, batch, pool, nullptr);
    k_fc<<<(N_GRAPHS * OUTD + 255) / 256, 256, 0, stream>>>(pool, batch, Wfc, bfc, out);
}